// Round 1
// baseline (26897.690 us; speedup 1.0000x reference)
//
#include <hip/hip_runtime.h>
#include <cstdint>
#include <cstddef>

#define BDIM 256
#define NWG  256

constexpr int B_ = 64, S_ = 1024, I_ = 128, H_ = 512, O_ = 128;
constexpr size_t HB = (size_t)H_ * B_;   // 32768 floats per slab [k][b]

// ---- workspace (floats): slabs ~1.06MB, optional XT +33.5MB ----
constexpr size_t Y1_OFF  = 0;             // 2 slots (ring): y1[t] at slot t&1, seed y1[-1] at slot 1
constexpr size_t Y2_OFF  = Y1_OFF + 2 * HB;
constexpr size_t RH0_OFF = Y2_OFF + 2 * HB;
constexpr size_t RH1_OFF = RH0_OFF + HB;
constexpr size_t Z0_OFF  = RH1_OFF + HB;
constexpr size_t Z1_OFF  = Z0_OFF + HB;
constexpr size_t BAR_OFF = Z1_OFF + HB;   // tree barrier: 34 lines x 64 uints
constexpr size_t BAR_WORDS = 34 * 64;
constexpr size_t SLAB_TOT = BAR_OFF + BAR_WORDS;
constexpr size_t XT_OFF  = SLAB_TOT;      // [t][i][b] transposed input (immutable during scan)
constexpr size_t XT_FLOATS = (size_t)S_ * I_ * B_;
constexpr size_t WS_NEED_XT_BYTES = (XT_OFF + XT_FLOATS) * 4;

// ---------------- LLC (agent-scope) STORE helper ----------------
// Stores of mutable cross-WG data remain agent-scope (LLC) atomics: they bypass
// L1/L2, so no L2 line is ever dirty for slab data and the release side of the
// grid barrier needs NO buffer_wbl2 writeback. READS of mutable data are now
// normal cached loads; staleness is handled by ONE agent-scope acquire fence
// (buffer_inv) per grid barrier, after which each XCD's L2 refetches fresh
// lines from the LLC and serves all 32 CUs on that XCD (broadcast amplification
// the atomic-load path could not provide).
__device__ __forceinline__ void llc_storef(float* p, float x) {
  union { float f; unsigned int u; } c; c.f = x;
  __hip_atomic_store((unsigned int*)p, c.u, __ATOMIC_RELAXED, __HIP_MEMORY_SCOPE_AGENT);
}
__device__ __forceinline__ float llc_loadf(const float* p) {
  unsigned int u = __hip_atomic_load((const unsigned int*)p, __ATOMIC_RELAXED,
                                     __HIP_MEMORY_SCOPE_AGENT);
  union { unsigned int u; float f; } c; c.u = u;
  return c.f;
}

// ---------------- init: seed ring slot-1 with h0, zero barrier ----------------
__global__ void k_init(const float* __restrict__ hidden, float* __restrict__ ws) {
  int idx = blockIdx.x * 256 + threadIdx.x;           // 2*HB + BAR_WORDS items
  if (idx < (int)(2 * HB)) {
    int l = idx >> 15, r = idx & 32767;
    int k = r >> 6, b = r & 63;
    ws[(l ? Y2_OFF : Y1_OFF) + HB + r] = hidden[b * 1024 + l * 512 + k];
  } else if (idx < (int)(2 * HB + BAR_WORDS)) {
    ((unsigned int*)(ws + BAR_OFF))[idx - 2 * HB] = 0u;
  }
}

// ---------------- input transpose: XT[t][i][b] = input[b][t][i] ----------------
__global__ void k_transpose_x(const float* __restrict__ in, float* __restrict__ Xt) {
  const size_t NQ = (size_t)B_ * S_ * I_ / 4;
  for (size_t q = (size_t)blockIdx.x * blockDim.x + threadIdx.x; q < NQ;
       q += (size_t)gridDim.x * blockDim.x) {
    int i4 = (int)(q & 31);
    int t  = (int)((q >> 5) & 1023);
    int b  = (int)(q >> 15);
    float4 v = *(const float4*)(in + ((size_t)b * 1024 + t) * 128 + i4 * 4);
    float* dst = Xt + (size_t)t * 8192 + (size_t)(i4 * 4) * 64 + b;
    dst[0] = v.x; dst[64] = v.y; dst[128] = v.z; dst[192] = v.w;
  }
}

// ---------------- dot helpers ----------------
__device__ __forceinline__ void fmas(float4& a, float s, const float4 h) {
  a.x = fmaf(s, h.x, a.x); a.y = fmaf(s, h.y, a.y);
  a.z = fmaf(s, h.z, a.z); a.w = fmaf(s, h.w, a.w);
}

// C=8 dot, normal cached loads (slabs are coherent-by-fence; XT immutable)
__device__ __forceinline__ void dotA8c(const float* __restrict__ src, const float* __restrict__ wAp,
                                       int nch, int kt, int b4, float4* acc) {
  #pragma unroll 8
  for (int ch = 0; ch < nch; ++ch) {
    int kk = ch * 16 + kt;
    float4 h = *(const float4*)(src + (size_t)kk * 64 + b4);
    const float* wp = wAp + kk * 8;
    float4 w0 = *(const float4*)wp;
    float4 w1 = *(const float4*)(wp + 4);
    fmas(acc[0], w0.x, h); fmas(acc[1], w0.y, h); fmas(acc[2], w0.z, h); fmas(acc[3], w0.w, h);
    fmas(acc[4], w1.x, h); fmas(acc[5], w1.y, h); fmas(acc[6], w1.z, h); fmas(acc[7], w1.w, h);
  }
}

// C=8, x directly from original [b][t][i] layout (fallback; immutable)
__device__ __forceinline__ void dotA8x(const float* __restrict__ xin, int tau,
                                       const float* __restrict__ wAp, int kt, int b4, float4* acc) {
  #pragma unroll 2
  for (int ch = 0; ch < 8; ++ch) {
    int i = ch * 16 + kt;
    float4 h;
    h.x = xin[(size_t)(b4 + 0) * 131072 + tau * 128 + i];
    h.y = xin[(size_t)(b4 + 1) * 131072 + tau * 128 + i];
    h.z = xin[(size_t)(b4 + 2) * 131072 + tau * 128 + i];
    h.w = xin[(size_t)(b4 + 3) * 131072 + tau * 128 + i];
    const float* wp = wAp + i * 8;
    float4 w0 = *(const float4*)wp;
    float4 w1 = *(const float4*)(wp + 4);
    fmas(acc[0], w0.x, h); fmas(acc[1], w0.y, h); fmas(acc[2], w0.z, h); fmas(acc[3], w0.w, h);
    fmas(acc[4], w1.x, h); fmas(acc[5], w1.y, h); fmas(acc[6], w1.z, h); fmas(acc[7], w1.w, h);
  }
}

// C=4 dot, normal cached loads
__device__ __forceinline__ void dotB4c(const float* __restrict__ src, const float* __restrict__ wBp,
                                       int nch, int kt, int b4, float4* acc) {
  #pragma unroll 8
  for (int ch = 0; ch < nch; ++ch) {
    int kk = ch * 16 + kt;
    float4 h = *(const float4*)(src + (size_t)kk * 64 + b4);
    const float* wp = wBp + kk * 4;
    float4 w0 = *(const float4*)wp;
    fmas(acc[0], w0.x, h); fmas(acc[1], w0.y, h); fmas(acc[2], w0.z, h); fmas(acc[3], w0.w, h);
  }
}

__device__ __forceinline__ void dotB4x(const float* __restrict__ xin, int tau,
                                       const float* __restrict__ wBp, int kt, int b4, float4* acc) {
  #pragma unroll 2
  for (int ch = 0; ch < 8; ++ch) {
    int i = ch * 16 + kt;
    float4 h;
    h.x = xin[(size_t)(b4 + 0) * 131072 + tau * 128 + i];
    h.y = xin[(size_t)(b4 + 1) * 131072 + tau * 128 + i];
    h.z = xin[(size_t)(b4 + 2) * 131072 + tau * 128 + i];
    h.w = xin[(size_t)(b4 + 3) * 131072 + tau * 128 + i];
    const float* wp = wBp + i * 4;
    float4 w0 = *(const float4*)wp;
    fmas(acc[0], w0.x, h); fmas(acc[1], w0.y, h); fmas(acc[2], w0.z, h); fmas(acc[3], w0.w, h);
  }
}

// ---- two-level tree barrier: 16 groups x 16 WGs, cumulative counters ----
// Producers' slab stores are agent-scope atomics, drained to the LLC by the
// compiler-inserted s_waitcnt vmcnt(0) at the first __syncthreads(), so the
// arrive/release needs no extra fence. On the CONSUMER side we now read slabs
// with normal cached loads, so after the global release we execute ONE
// agent-scope acquire fence (s_waitcnt + buffer_inv): drops stale clean L1/L2
// lines; fresh data is refetched from the LLC where every store landed.
__device__ __forceinline__ void grid_barrier(unsigned int* bar, unsigned int ph) {
  __syncthreads();
  asm volatile("" ::: "memory");
  if (threadIdx.x == 0) {
    const int g = (int)(blockIdx.x >> 4);
    unsigned int* grp_cnt  = bar + (size_t)g * 64;
    unsigned int* root_cnt = bar + 16 * 64;
    unsigned int* grp_gen  = bar + (size_t)(17 + g) * 64;
    unsigned int* root_gen = bar + 33 * 64;
    unsigned int r = __hip_atomic_fetch_add(grp_cnt, 1u, __ATOMIC_RELAXED, __HIP_MEMORY_SCOPE_AGENT);
    if (r == 16u * ph - 1u) {          // last of my group this phase
      unsigned int rr = __hip_atomic_fetch_add(root_cnt, 1u, __ATOMIC_RELAXED, __HIP_MEMORY_SCOPE_AGENT);
      if (rr == 16u * ph - 1u) {       // last group overall: release root
        __hip_atomic_store(root_gen, ph, __ATOMIC_RELAXED, __HIP_MEMORY_SCOPE_AGENT);
      } else {
        while (__hip_atomic_load(root_gen, __ATOMIC_RELAXED, __HIP_MEMORY_SCOPE_AGENT) < ph)
          __builtin_amdgcn_s_sleep(1);
      }
      __hip_atomic_store(grp_gen, ph, __ATOMIC_RELAXED, __HIP_MEMORY_SCOPE_AGENT);
    } else {
      while (__hip_atomic_load(grp_gen, __ATOMIC_RELAXED, __HIP_MEMORY_SCOPE_AGENT) < ph)
        __builtin_amdgcn_s_sleep(1);
    }
  }
  asm volatile("" ::: "memory");
  __syncthreads();
  // acquire: invalidate stale clean L1/L2 copies of slab lines before reading
  __builtin_amdgcn_fence(__ATOMIC_ACQUIRE, "agent");
  asm volatile("" ::: "memory");
}

// ---------------- persistent scan: weights LDS-resident across all stages ----------------
struct ScanArgs {
  float* ws;
  const float* xin;
  float* out;
  const float *Wzx0, *Wzh0, *bz0, *Wrx0, *Wrh0, *br0, *Wgx0, *Wgh0, *bg0;
  const float *Wzx1, *Wzh1, *bz1, *Wrx1, *Wrh1, *br1, *Wgx1, *Wgh1, *bg1;
  const float *Wout, *bout;
  int use_xt;
};

__launch_bounds__(BDIM, 1)
__global__ void k_scan(ScanArgs a) {
  float* ws = a.ws;
  unsigned int* bar = (unsigned int*)(ws + BAR_OFF);

  const int tid = threadIdx.x;
  const int wg  = blockIdx.x;
  const int kt  = tid >> 4;          // 0..15 (k-thread)
  const int bq  = tid & 15;          // 0..15 (batch quad)
  const int b4  = bq << 2;           // batch base (4 consecutive b)

  // phase A assignment: wg>>6 -> {L0z, L0r, L1z, L1r}, 8 cols each
  const int mA  = wg >> 6;
  const int lA  = mA >> 1;           // layer
  const int gA  = mA & 1;            // 0 z, 1 r
  const int jA0 = (wg & 63) * 8;
  const int KA  = (mA < 2) ? 640 : 1024;
  // phase B assignment: wg>>7 -> {L0g, L1g}, 4 cols each
  const int mB  = wg >> 7;
  const int jB0 = (wg & 127) * 4;
  const int KB  = mB ? 1024 : 640;

  // LDS: weights resident for the whole scan + reduction scratch
  __shared__ float wA[8192];         // [k][8] for this WG's A matrix (KA*8 used)
  __shared__ float wB[4096];         // [k][4] for this WG's g matrix (KB*4 used)
  __shared__ float wO[512];          // outproj column (wg<128)
  __shared__ float pA[9 * 64 * 17];  // partials: [c(9)][b(64)][kt(17 padded)]

  {  // one-time gather of this WG's weight columns (cached loads; immutable)
    const float* A0 = lA ? (gA ? a.Wrx1 : a.Wzx1) : (gA ? a.Wrh0 : a.Wzh0);
    const float* A1 = lA ? (gA ? a.Wrh1 : a.Wzh1) : (gA ? a.Wrx0 : a.Wzx0);
    for (int idx = tid; idx < KA * 8; idx += BDIM) {
      int k = idx >> 3, c = idx & 7;
      wA[idx] = (k < 512) ? A0[k * 512 + jA0 + c] : A1[(k - 512) * 512 + jA0 + c];
    }
    const float* B0 = mB ? a.Wgx1 : a.Wgh0;
    const float* B1 = mB ? a.Wgh1 : a.Wgx0;
    for (int idx = tid; idx < KB * 4; idx += BDIM) {
      int k = idx >> 2, c = idx & 3;
      wB[idx] = (k < 512) ? B0[k * 512 + jB0 + c] : B1[(k - 512) * 512 + jB0 + c];
    }
    if (wg < 128)
      for (int idx = tid; idx < 512; idx += BDIM) wO[idx] = a.Wout[(size_t)idx * 128 + wg];
  }
  // biases preloaded for reducer lanes
  const float* bAv = lA ? (gA ? a.br1 : a.bz1) : (gA ? a.br0 : a.bz0);
  const float biasA_0 = bAv[jA0 + (tid >> 6)];
  const float biasA_1 = bAv[jA0 + 4 + (tid >> 6)];
  const float biasB_0 = (mB ? a.bg1 : a.bg0)[jB0 + (tid >> 6)];
  const float boutW = (wg < 128) ? a.bout[wg] : 0.f;
  __syncthreads();

  const float* XT = ws + XT_OFF;
  unsigned int ph = 1;

  for (int tau = 0; tau <= S_ + 1; ++tau) {
    const bool doL0 = (tau < S_);
    const bool doL1 = (tau >= 1) && (tau <= S_);
    const int slotP = (tau + 1) & 1;    // y1[tau-1] slot; y2[tau-1] write slot
    const int slotQ = tau & 1;          // y2[tau-2] slot; y1[tau] write slot
    const float* y1p = ws + Y1_OFF + (size_t)slotP * HB;   // y1[tau-1]: L0 h_prev, L1 x
    const float* y2p = ws + Y2_OFF + (size_t)slotQ * HB;   // y2[tau-2]: L1 h_prev, outproj src
    float* y1w = ws + Y1_OFF + (size_t)slotQ * HB;
    float* y2w = ws + Y2_OFF + (size_t)slotP * HB;

    // ================= phase A: z & r (+ fused outproj of t=tau-2) =================
    const bool actA = lA ? doL1 : doL0;
    float4 acc[8];
    #pragma unroll
    for (int c = 0; c < 8; ++c) acc[c] = make_float4(0.f, 0.f, 0.f, 0.f);
    if (actA) {
      dotA8c(y1p, wA, 32, kt, b4, acc);                   // k in [0,512): y1[tau-1] both layers
      if (mA < 2) {                                       // L0: x region, k in [512,640)
        if (a.use_xt) dotA8c(XT + (size_t)tau * 8192, wA + 512 * 8, 8, kt, b4, acc);
        else          dotA8x(a.xin, tau, wA + 512 * 8, kt, b4, acc);
      } else {                                            // L1: h region, k in [512,1024)
        dotA8c(y2p, wA + 512 * 8, 32, kt, b4, acc);
      }
    }
    const bool doOut = (tau >= 2) && (wg < 128);
    float4 accO = make_float4(0.f, 0.f, 0.f, 0.f);
    if (doOut) {
      #pragma unroll 8
      for (int ch = 0; ch < 32; ++ch) {
        int kk = ch * 16 + kt;
        float4 h = *(const float4*)(y2p + (size_t)kk * 64 + b4);
        fmas(accO, wO[kk], h);
      }
    }
    // partial store + reduce
    if (actA) {
      #pragma unroll
      for (int c = 0; c < 8; ++c) {
        float pv[4] = {acc[c].x, acc[c].y, acc[c].z, acc[c].w};
        #pragma unroll
        for (int j = 0; j < 4; ++j) pA[(c * 64 + b4 + j) * 17 + kt] = pv[j];
      }
    }
    if (doOut) {
      float pv[4] = {accO.x, accO.y, accO.z, accO.w};
      #pragma unroll
      for (int j = 0; j < 4; ++j) pA[(512 + b4 + j) * 17 + kt] = pv[j];
    }
    __syncthreads();
    if (actA) {
      #pragma unroll
      for (int r = 0; r < 2; ++r) {
        int idx = tid + (r << 8);
        int c = idx >> 6, b = idx & 63;
        float s = r ? biasA_1 : biasA_0;
        #pragma unroll
        for (int q = 0; q < 16; ++q) s += pA[(c * 64 + b) * 17 + q];
        float v = 1.0f / (1.0f + __expf(-s));
        size_t jb = (size_t)(jA0 + c) * 64 + b;
        if (gA == 0) {
          llc_storef(ws + (lA ? Z1_OFF : Z0_OFF) + jb, v);
        } else {
          const float* hpsl = lA ? y2p : y1p;
          float hp = hpsl[jb];                            // cached; fresh since last acquire
          llc_storef(ws + (lA ? RH1_OFF : RH0_OFF) + jb, v * hp);
        }
      }
    }
    if (doOut && tid < 64) {
      float s = boutW;
      #pragma unroll
      for (int q = 0; q < 16; ++q) s += pA[(512 + tid) * 17 + q];
      a.out[((size_t)tid * 1024 + (tau - 2)) * 128 + wg] = s;
    }

    grid_barrier(bar, ph++);   // rh/z visible grid-wide (+ acquire-inv)

    // ================= phase B: g and h update =================
    const bool actB = mB ? doL1 : doL0;
    float4 accB[4];
    #pragma unroll
    for (int c = 0; c < 4; ++c) accB[c] = make_float4(0.f, 0.f, 0.f, 0.f);
    if (actB) {
      const float* r0 = mB ? y1p : (ws + RH0_OFF);        // k in [0,512)
      dotB4c(r0, wB, 32, kt, b4, accB);
      if (mB) {
        dotB4c(ws + RH1_OFF, wB + 512 * 4, 32, kt, b4, accB);
      } else {
        if (a.use_xt) dotB4c(XT + (size_t)tau * 8192, wB + 512 * 4, 8, kt, b4, accB);
        else          dotB4x(a.xin, tau, wB + 512 * 4, kt, b4, accB);
      }
      #pragma unroll
      for (int c = 0; c < 4; ++c) {
        float pv[4] = {accB[c].x, accB[c].y, accB[c].z, accB[c].w};
        #pragma unroll
        for (int j = 0; j < 4; ++j) pA[(c * 64 + b4 + j) * 17 + kt] = pv[j];
      }
    }
    __syncthreads();
    if (actB) {
      int c = tid >> 6, b = tid & 63;
      float s = biasB_0;
      #pragma unroll
      for (int q = 0; q < 16; ++q) s += pA[(c * 64 + b) * 17 + q];
      float g = tanhf(s);
      size_t jb = (size_t)(jB0 + c) * 64 + b;
      float z  = ws[(mB ? Z1_OFF : Z0_OFF) + jb];         // cached; fresh since last acquire
      float hp = (mB ? y2p : y1p)[jb];
      float hn = fmaf(z, hp - g, g);                      // z*hp + (1-z)*g
      llc_storef((mB ? y2w : y1w) + jb, hn);
    }

    grid_barrier(bar, ph++);   // h slabs visible for next stage (+ acquire-inv)
  }
}

// ---------------- final hidden states: out[BSO + b*1024 + l*512 + j] ----------------
__global__ void k_hidden(const float* __restrict__ ws, float* __restrict__ out) {
  int idx = blockIdx.x * 256 + threadIdx.x;   // 65536
  int b = idx >> 10, rem = idx & 1023, l = rem >> 9, j = rem & 511;
  // y1[1023] at slot 1; y2[1023] written stage 1024 at slot (1024+1)&1 = 1
  const float* src = ws + (l ? Y2_OFF : Y1_OFF) + HB + (size_t)j * 64 + b;
  out[(size_t)B_ * S_ * O_ + idx] = *src;
}

// ---------------- launch ----------------
extern "C" void kernel_launch(void* const* d_in, const int* in_sizes, int n_in,
                              void* d_out, int out_size, void* d_ws, size_t ws_size,
                              hipStream_t stream) {
  const float* input  = (const float*)d_in[0];
  const float* hidden = (const float*)d_in[1];
  const float* Wzx0 = (const float*)d_in[2],  *Wzh0 = (const float*)d_in[3],  *bz0 = (const float*)d_in[4];
  const float* Wrx0 = (const float*)d_in[5],  *Wrh0 = (const float*)d_in[6],  *br0 = (const float*)d_in[7];
  const float* Wgx0 = (const float*)d_in[8],  *Wgh0 = (const float*)d_in[9],  *bg0 = (const float*)d_in[10];
  const float* Wzx1 = (const float*)d_in[11], *Wzh1 = (const float*)d_in[12], *bz1 = (const float*)d_in[13];
  const float* Wrx1 = (const float*)d_in[14], *Wrh1 = (const float*)d_in[15], *br1 = (const float*)d_in[16];
  const float* Wgx1 = (const float*)d_in[17], *Wgh1 = (const float*)d_in[18], *bg1 = (const float*)d_in[19];
  const float* Wout = (const float*)d_in[20], *bout = (const float*)d_in[21];
  float* ws = (float*)d_ws;
  float* out = (float*)d_out;

  const int use_xt = (ws_size >= WS_NEED_XT_BYTES) ? 1 : 0;

  k_init<<<265, BDIM, 0, stream>>>(hidden, ws);
  if (use_xt) k_transpose_x<<<2048, BDIM, 0, stream>>>(input, ws + XT_OFF);

  ScanArgs sa{ws, input, out,
              Wzx0, Wzh0, bz0, Wrx0, Wrh0, br0, Wgx0, Wgh0, bg0,
              Wzx1, Wzh1, bz1, Wrx1, Wrh1, br1, Wgx1, Wgh1, bg1,
              Wout, bout, use_xt};
  k_scan<<<dim3(NWG), dim3(BDIM), 0, stream>>>(sa);

  k_hidden<<<256, 256, 0, stream>>>(ws, out);
}

// Round 2
// 25290.485 us; speedup vs baseline: 1.0635x; 1.0635x over previous
//
#include <hip/hip_runtime.h>
#include <cstdint>
#include <cstddef>

#define BDIM 512
#define NWG  128

constexpr int B_ = 64, S_ = 1024, I_ = 128, H_ = 512, O_ = 128;
constexpr size_t HB = (size_t)H_ * B_;   // 32768 floats per slab [k][b]

// ---- workspace (floats): slabs ~1.06MB, optional XT +33.5MB ----
constexpr size_t Y1_OFF  = 0;             // 2 slots (ring): y1[t] at slot t&1, seed y1[-1] at slot 1
constexpr size_t Y2_OFF  = Y1_OFF + 2 * HB;
constexpr size_t RH0_OFF = Y2_OFF + 2 * HB;
constexpr size_t RH1_OFF = RH0_OFF + HB;
constexpr size_t Z0_OFF  = RH1_OFF + HB;
constexpr size_t Z1_OFF  = Z0_OFF + HB;
constexpr size_t BAR_OFF = Z1_OFF + HB;   // barrier: 34 lines x 64 uints
constexpr size_t BAR_WORDS = 34 * 64;
constexpr size_t SLAB_TOT = BAR_OFF + BAR_WORDS;
constexpr size_t XT_OFF  = SLAB_TOT;      // [t][i][b] transposed input (immutable during scan)
constexpr size_t XT_FLOATS = (size_t)S_ * I_ * B_;
constexpr size_t WS_NEED_XT_BYTES = (XT_OFF + XT_FLOATS) * 4;

// ---------------- LLC (agent-scope, L2-bypassing) access helpers ----------------
__device__ __forceinline__ float4 llc_load4(const float* p) {
  const unsigned long long* q = (const unsigned long long*)p;
  unsigned long long lo = __hip_atomic_load(q,     __ATOMIC_RELAXED, __HIP_MEMORY_SCOPE_AGENT);
  unsigned long long hi = __hip_atomic_load(q + 1, __ATOMIC_RELAXED, __HIP_MEMORY_SCOPE_AGENT);
  union { unsigned long long u[2]; float4 v; } c;
  c.u[0] = lo; c.u[1] = hi;
  return c.v;
}
__device__ __forceinline__ void llc_store4(float* p, float4 v) {
  union { float4 v; unsigned long long u[2]; } c; c.v = v;
  __hip_atomic_store((unsigned long long*)p,     c.u[0], __ATOMIC_RELAXED, __HIP_MEMORY_SCOPE_AGENT);
  __hip_atomic_store((unsigned long long*)p + 1, c.u[1], __ATOMIC_RELAXED, __HIP_MEMORY_SCOPE_AGENT);
}

// ---------------- init: seed ring slot-1 with h0, zero barrier ----------------
__global__ void k_init(const float* __restrict__ hidden, float* __restrict__ ws) {
  int idx = blockIdx.x * 256 + threadIdx.x;           // 2*HB + BAR_WORDS items
  if (idx < (int)(2 * HB)) {
    int l = idx >> 15, r = idx & 32767;
    int k = r >> 6, b = r & 63;
    ws[(l ? Y2_OFF : Y1_OFF) + HB + r] = hidden[b * 1024 + l * 512 + k];
  } else if (idx < (int)(2 * HB + BAR_WORDS)) {
    ((unsigned int*)(ws + BAR_OFF))[idx - 2 * HB] = 0u;
  }
}

// ---------------- input transpose: XT[t][i][b] = input[b][t][i] ----------------
__global__ void k_transpose_x(const float* __restrict__ in, float* __restrict__ Xt) {
  const size_t NQ = (size_t)B_ * S_ * I_ / 4;
  for (size_t q = (size_t)blockIdx.x * blockDim.x + threadIdx.x; q < NQ;
       q += (size_t)gridDim.x * blockDim.x) {
    int i4 = (int)(q & 31);
    int t  = (int)((q >> 5) & 1023);
    int b  = (int)(q >> 15);
    float4 v = *(const float4*)(in + ((size_t)b * 1024 + t) * 128 + i4 * 4);
    float* dst = Xt + (size_t)t * 8192 + (size_t)(i4 * 4) * 64 + b;
    dst[0] = v.x; dst[64] = v.y; dst[128] = v.z; dst[192] = v.w;
  }
}

// ---------------- fma helpers ----------------
__device__ __forceinline__ void fmas(float4& a, float s, const float4 h) {
  a.x = fmaf(s, h.x, a.x); a.y = fmaf(s, h.y, a.y);
  a.z = fmaf(s, h.z, a.z); a.w = fmaf(s, h.w, a.w);
}
__device__ __forceinline__ void fma16(float4* acc, const float* wp, float4 h) {
  float4 w0 = *(const float4*)wp,       w1 = *(const float4*)(wp + 4);
  float4 w2 = *(const float4*)(wp + 8), w3 = *(const float4*)(wp + 12);
  fmas(acc[0],  w0.x, h); fmas(acc[1],  w0.y, h); fmas(acc[2],  w0.z, h); fmas(acc[3],  w0.w, h);
  fmas(acc[4],  w1.x, h); fmas(acc[5],  w1.y, h); fmas(acc[6],  w1.z, h); fmas(acc[7],  w1.w, h);
  fmas(acc[8],  w2.x, h); fmas(acc[9],  w2.y, h); fmas(acc[10], w2.z, h); fmas(acc[11], w2.w, h);
  fmas(acc[12], w3.x, h); fmas(acc[13], w3.y, h); fmas(acc[14], w3.z, h); fmas(acc[15], w3.w, h);
}
__device__ __forceinline__ void fma8(float4* acc, const float* wp, float4 h) {
  float4 w0 = *(const float4*)wp, w1 = *(const float4*)(wp + 4);
  fmas(acc[0], w0.x, h); fmas(acc[1], w0.y, h); fmas(acc[2], w0.z, h); fmas(acc[3], w0.w, h);
  fmas(acc[4], w1.x, h); fmas(acc[5], w1.y, h); fmas(acc[6], w1.z, h); fmas(acc[7], w1.w, h);
}
// butterfly reduce over lane-bits 4,5 (the kt_lo bits): after this all lanes hold the sum
__device__ __forceinline__ void wred(float4& v) {
  v.x += __shfl_xor(v.x, 16); v.y += __shfl_xor(v.y, 16);
  v.z += __shfl_xor(v.z, 16); v.w += __shfl_xor(v.w, 16);
  v.x += __shfl_xor(v.x, 32); v.y += __shfl_xor(v.y, 32);
  v.z += __shfl_xor(v.z, 32); v.w += __shfl_xor(v.w, 32);
}

// ---- tree barrier: 8 groups x 16 WGs arrival; flat root-flag release ----
// All mutable cross-WG data moves via agent-scope (LLC) atomics: no stale L2
// copies exist, so no cache maintenance needed. __syncthreads() drains
// vmcnt(0) (compiler-inserted), so every wave's LLC stores complete before
// lane 0 arrives.
__device__ __forceinline__ void grid_barrier(unsigned int* bar, unsigned int ph) {
  __syncthreads();
  asm volatile("" ::: "memory");
  if (threadIdx.x == 0) {
    const int g = (int)(blockIdx.x >> 4);                 // 8 groups of 16
    unsigned int* grp_cnt  = bar + (size_t)g * 64;
    unsigned int* root_cnt = bar + 16 * 64;
    unsigned int* root_gen = bar + 33 * 64;
    bool released = false;
    unsigned int r = __hip_atomic_fetch_add(grp_cnt, 1u, __ATOMIC_RELAXED, __HIP_MEMORY_SCOPE_AGENT);
    if (r == 16u * ph - 1u) {          // last of my group this phase
      unsigned int rr = __hip_atomic_fetch_add(root_cnt, 1u, __ATOMIC_RELAXED, __HIP_MEMORY_SCOPE_AGENT);
      if (rr == 8u * ph - 1u) {        // last group overall: release
        __hip_atomic_store(root_gen, ph, __ATOMIC_RELAXED, __HIP_MEMORY_SCOPE_AGENT);
        released = true;
      }
    }
    if (!released)
      while (__hip_atomic_load(root_gen, __ATOMIC_RELAXED, __HIP_MEMORY_SCOPE_AGENT) < ph)
        __builtin_amdgcn_s_sleep(1);
  }
  asm volatile("" ::: "memory");
  __syncthreads();
}

// ---------------- persistent scan ----------------
struct ScanArgs {
  float* ws;
  const float* xin;
  float* out;
  const float *Wzx0, *Wzh0, *bz0, *Wrx0, *Wrh0, *br0, *Wgx0, *Wgh0, *bg0;
  const float *Wzx1, *Wzh1, *bz1, *Wrx1, *Wrh1, *br1, *Wgx1, *Wgh1, *bg1;
  const float *Wout, *bout;
  int use_xt;
};

__launch_bounds__(BDIM, 1)
__global__ void k_scan(ScanArgs a) {
  float* ws = a.ws;
  unsigned int* bar = (unsigned int*)(ws + BAR_OFF);

  const int tid  = threadIdx.x;
  const int wg   = blockIdx.x;
  const int kt   = tid >> 4;         // 0..31 (k-thread)
  const int b4   = (tid & 15) << 2;  // batch base (4 consecutive b)
  const int lane = tid & 63;
  const int wv   = tid >> 6;         // wave id 0..7

  // phase A: wg>>5 -> {L0z, L0r, L1z, L1r}, 16 cols each
  const int  mA    = wg >> 5;
  const int  lA    = mA >> 1;
  const int  gA    = mA & 1;
  const int  jA0   = (wg & 31) * 16;
  const int  KA    = (mA < 2) ? 640 : 1024;
  const bool isL1A = (mA >= 2);
  // phase B swapped for balance: wg<64 (light A) -> L1g (heavy B); wg>=64 -> L0g
  const int  mB  = (wg < 64) ? 1 : 0;
  const int  jB0 = (wg & 63) * 8;
  const int  KB  = mB ? 1024 : 640;
  // outproj: 2 cols per L1-A WG (folds into the y2p dot)
  const int  jO  = (wg & 63) * 2;

  __shared__ float  wA[16384];        // [k][16], 64KB
  __shared__ float  wB[8192];         // [k][8], 32KB
  __shared__ float  wO[1024];         // [k][2] outproj cols (L1 WGs), 4KB
  __shared__ float4 pR4[2592];        // partials [c(18)][q(16)][w(8) pad 9], 40.5KB

  {  // one-time weight gather (cached loads; immutable)
    const float* A0 = lA ? (gA ? a.Wrx1 : a.Wzx1) : (gA ? a.Wrh0 : a.Wzh0);
    const float* A1 = lA ? (gA ? a.Wrh1 : a.Wzh1) : (gA ? a.Wrx0 : a.Wzx0);
    for (int idx = tid; idx < KA * 16; idx += BDIM) {
      int k = idx >> 4, c = idx & 15;
      wA[idx] = (k < 512) ? A0[k * 512 + jA0 + c] : A1[(k - 512) * 512 + jA0 + c];
    }
    const float* B0 = mB ? a.Wgx1 : a.Wgh0;
    const float* B1 = mB ? a.Wgh1 : a.Wgx0;
    for (int idx = tid; idx < KB * 8; idx += BDIM) {
      int k = idx >> 3, c = idx & 7;
      wB[idx] = (k < 512) ? B0[k * 512 + jB0 + c] : B1[(k - 512) * 512 + jB0 + c];
    }
    if (isL1A)
      for (int idx = tid; idx < 1024; idx += BDIM)
        wO[idx] = a.Wout[(size_t)(idx >> 1) * 128 + jO + (idx & 1)];
  }
  const float* bAv = lA ? (gA ? a.br1 : a.bz1) : (gA ? a.br0 : a.bz0);
  float biasA_c = 0.f, biasB_c = 0.f, boutc = 0.f;
  if (tid < 256) biasA_c = bAv[jA0 + (tid >> 4)];
  if (tid < 128) biasB_c = (mB ? a.bg1 : a.bg0)[jB0 + (tid >> 4)];
  if (isL1A && tid >= 256 && tid < 288) boutc = a.bout[jO + ((tid >> 4) & 1)];
  __syncthreads();

  const float* XT = ws + XT_OFF;
  unsigned int ph = 1;

  for (int tau = 0; tau <= S_ + 1; ++tau) {
    const bool doL0 = (tau < S_);
    const bool doL1 = (tau >= 1) && (tau <= S_);
    const int slotP = (tau + 1) & 1;
    const int slotQ = tau & 1;
    const float* y1p = ws + Y1_OFF + (size_t)slotP * HB;   // y1[tau-1]
    const float* y2p = ws + Y2_OFF + (size_t)slotQ * HB;   // y2[tau-2]
    float* y1w = ws + Y1_OFF + (size_t)slotQ * HB;
    float* y2w = ws + Y2_OFF + (size_t)slotP * HB;

    // ================= phase A: z & r (+ fused outproj on L1 WGs) =================
    const bool actL = isL1A ? doL1 : doL0;
    const bool outW = isL1A && (tau >= 2);
    float4 acc[16];
    #pragma unroll
    for (int c = 0; c < 16; ++c) acc[c] = make_float4(0.f, 0.f, 0.f, 0.f);
    float4 accO0 = make_float4(0.f, 0.f, 0.f, 0.f);
    float4 accO1 = make_float4(0.f, 0.f, 0.f, 0.f);

    if (actL) {                       // region 1: y1p, k in [0,512)
      #pragma unroll 8
      for (int ch = 0; ch < 16; ++ch) {
        const int kk = ch * 32 + kt;
        float4 h = llc_load4(y1p + (size_t)kk * 64 + b4);
        fma16(acc, wA + kk * 16, h);
      }
    }
    if (isL1A) {                      // region 2 L1: y2p, k in [512,1024), + outproj fold
      if (actL || outW) {
        #pragma unroll 8
        for (int ch = 0; ch < 16; ++ch) {
          const int kk = ch * 32 + kt;
          float4 h = llc_load4(y2p + (size_t)kk * 64 + b4);
          fma16(acc, wA + (512 + kk) * 16, h);
          float2 wo = *(const float2*)(wO + kk * 2);
          fmas(accO0, wo.x, h); fmas(accO1, wo.y, h);
        }
      }
    } else if (actL) {                // region 2 L0: x, k in [512,640)
      if (a.use_xt) {
        const float* XTt = XT + (size_t)tau * 8192;
        #pragma unroll 4
        for (int ch = 0; ch < 4; ++ch) {
          const int kk = ch * 32 + kt;   // 0..127
          float4 h = *(const float4*)(XTt + (size_t)kk * 64 + b4);
          fma16(acc, wA + (512 + kk) * 16, h);
        }
      } else {
        #pragma unroll 2
        for (int ch = 0; ch < 4; ++ch) {
          const int i = ch * 32 + kt;
          float4 h;
          h.x = a.xin[(size_t)(b4 + 0) * 131072 + (size_t)tau * 128 + i];
          h.y = a.xin[(size_t)(b4 + 1) * 131072 + (size_t)tau * 128 + i];
          h.z = a.xin[(size_t)(b4 + 2) * 131072 + (size_t)tau * 128 + i];
          h.w = a.xin[(size_t)(b4 + 3) * 131072 + (size_t)tau * 128 + i];
          fma16(acc, wA + (512 + i) * 16, h);
        }
      }
    }
    // intra-wave reduce (kt_lo bits) + cross-wave partials in LDS
    if (actL) {
      #pragma unroll
      for (int c = 0; c < 16; ++c) wred(acc[c]);
    }
    if (outW) { wred(accO0); wred(accO1); }
    if (lane < 16) {
      if (actL) {
        #pragma unroll
        for (int c = 0; c < 16; ++c) pR4[(c * 16 + lane) * 9 + wv] = acc[c];
      }
      if (outW) {
        pR4[(256 + lane) * 9 + wv] = accO0;
        pR4[(272 + lane) * 9 + wv] = accO1;
      }
    }
    __syncthreads();
    if (actL && tid < 256) {
      const int c = tid >> 4, q = tid & 15;
      float4 s = make_float4(biasA_c, biasA_c, biasA_c, biasA_c);
      #pragma unroll
      for (int w = 0; w < 8; ++w) {
        float4 p = pR4[(c * 16 + q) * 9 + w];
        s.x += p.x; s.y += p.y; s.z += p.z; s.w += p.w;
      }
      float4 v;
      v.x = 1.0f / (1.0f + __expf(-s.x)); v.y = 1.0f / (1.0f + __expf(-s.y));
      v.z = 1.0f / (1.0f + __expf(-s.z)); v.w = 1.0f / (1.0f + __expf(-s.w));
      const size_t jb = (size_t)(jA0 + c) * 64 + q * 4;
      if (gA == 0) {
        llc_store4(ws + (lA ? Z1_OFF : Z0_OFF) + jb, v);
      } else {
        float4 hp = llc_load4((lA ? y2p : y1p) + jb);
        v.x *= hp.x; v.y *= hp.y; v.z *= hp.z; v.w *= hp.w;
        llc_store4(ws + (lA ? RH1_OFF : RH0_OFF) + jb, v);
      }
    }
    if (outW && tid >= 256 && tid < 288) {
      const int oc = (tid >> 4) & 1, q = tid & 15;
      float4 s = make_float4(boutc, boutc, boutc, boutc);
      #pragma unroll
      for (int w = 0; w < 8; ++w) {
        float4 p = pR4[((16 + oc) * 16 + q) * 9 + w];
        s.x += p.x; s.y += p.y; s.z += p.z; s.w += p.w;
      }
      const size_t obase = ((size_t)(q * 4) * 1024 + (tau - 2)) * 128 + jO + oc;
      a.out[obase]          = s.x;
      a.out[obase + 131072] = s.y;
      a.out[obase + 262144] = s.z;
      a.out[obase + 393216] = s.w;
    }

    grid_barrier(bar, ph++);   // rh/z visible grid-wide

    // ================= phase B: g and h update =================
    const bool actB = mB ? doL1 : doL0;
    float4 accB[8];
    #pragma unroll
    for (int c = 0; c < 8; ++c) accB[c] = make_float4(0.f, 0.f, 0.f, 0.f);
    if (actB) {
      const float* r0 = mB ? y1p : (ws + RH0_OFF);
      #pragma unroll 8
      for (int ch = 0; ch < 16; ++ch) {
        const int kk = ch * 32 + kt;
        float4 h = llc_load4(r0 + (size_t)kk * 64 + b4);
        fma8(accB, wB + kk * 8, h);
      }
      if (mB) {
        #pragma unroll 8
        for (int ch = 0; ch < 16; ++ch) {
          const int kk = ch * 32 + kt;
          float4 h = llc_load4(ws + RH1_OFF + (size_t)kk * 64 + b4);
          fma8(accB, wB + (512 + kk) * 8, h);
        }
      } else if (a.use_xt) {
        const float* XTt = XT + (size_t)tau * 8192;
        #pragma unroll 4
        for (int ch = 0; ch < 4; ++ch) {
          const int kk = ch * 32 + kt;
          float4 h = *(const float4*)(XTt + (size_t)kk * 64 + b4);
          fma8(accB, wB + (512 + kk) * 8, h);
        }
      } else {
        #pragma unroll 2
        for (int ch = 0; ch < 4; ++ch) {
          const int i = ch * 32 + kt;
          float4 h;
          h.x = a.xin[(size_t)(b4 + 0) * 131072 + (size_t)tau * 128 + i];
          h.y = a.xin[(size_t)(b4 + 1) * 131072 + (size_t)tau * 128 + i];
          h.z = a.xin[(size_t)(b4 + 2) * 131072 + (size_t)tau * 128 + i];
          h.w = a.xin[(size_t)(b4 + 3) * 131072 + (size_t)tau * 128 + i];
          fma8(accB, wB + (512 + i) * 8, h);
        }
      }
      #pragma unroll
      for (int c = 0; c < 8; ++c) wred(accB[c]);
      if (lane < 16) {
        #pragma unroll
        for (int c = 0; c < 8; ++c) pR4[(c * 16 + lane) * 9 + wv] = accB[c];
      }
    }
    __syncthreads();
    if (actB && tid < 128) {
      const int c = tid >> 4, q = tid & 15;
      float4 s = make_float4(biasB_c, biasB_c, biasB_c, biasB_c);
      #pragma unroll
      for (int w = 0; w < 8; ++w) {
        float4 p = pR4[(c * 16 + q) * 9 + w];
        s.x += p.x; s.y += p.y; s.z += p.z; s.w += p.w;
      }
      float4 g;
      g.x = tanhf(s.x); g.y = tanhf(s.y); g.z = tanhf(s.z); g.w = tanhf(s.w);
      const size_t jb = (size_t)(jB0 + c) * 64 + q * 4;
      float4 z  = llc_load4(ws + (mB ? Z1_OFF : Z0_OFF) + jb);
      float4 hp = llc_load4((mB ? y2p : y1p) + jb);
      float4 hn;
      hn.x = fmaf(z.x, hp.x - g.x, g.x);
      hn.y = fmaf(z.y, hp.y - g.y, g.y);
      hn.z = fmaf(z.z, hp.z - g.z, g.z);
      hn.w = fmaf(z.w, hp.w - g.w, g.w);
      llc_store4((mB ? y2w : y1w) + jb, hn);
    }

    grid_barrier(bar, ph++);   // h slabs visible for next stage
  }
}

// ---------------- final hidden states: out[BSO + b*1024 + l*512 + j] ----------------
__global__ void k_hidden(const float* __restrict__ ws, float* __restrict__ out) {
  int idx = blockIdx.x * 256 + threadIdx.x;   // 65536
  int b = idx >> 10, rem = idx & 1023, l = rem >> 9, j = rem & 511;
  const float* src = ws + (l ? Y2_OFF : Y1_OFF) + HB + (size_t)j * 64 + b;
  out[(size_t)B_ * S_ * O_ + idx] = *src;
}

// ---------------- launch ----------------
extern "C" void kernel_launch(void* const* d_in, const int* in_sizes, int n_in,
                              void* d_out, int out_size, void* d_ws, size_t ws_size,
                              hipStream_t stream) {
  const float* input  = (const float*)d_in[0];
  const float* hidden = (const float*)d_in[1];
  const float* Wzx0 = (const float*)d_in[2],  *Wzh0 = (const float*)d_in[3],  *bz0 = (const float*)d_in[4];
  const float* Wrx0 = (const float*)d_in[5],  *Wrh0 = (const float*)d_in[6],  *br0 = (const float*)d_in[7];
  const float* Wgx0 = (const float*)d_in[8],  *Wgh0 = (const float*)d_in[9],  *bg0 = (const float*)d_in[10];
  const float* Wzx1 = (const float*)d_in[11], *Wzh1 = (const float*)d_in[12], *bz1 = (const float*)d_in[13];
  const float* Wrx1 = (const float*)d_in[14], *Wrh1 = (const float*)d_in[15], *br1 = (const float*)d_in[16];
  const float* Wgx1 = (const float*)d_in[17], *Wgh1 = (const float*)d_in[18], *bg1 = (const float*)d_in[19];
  const float* Wout = (const float*)d_in[20], *bout = (const float*)d_in[21];
  float* ws = (float*)d_ws;
  float* out = (float*)d_out;

  const int use_xt = (ws_size >= WS_NEED_XT_BYTES) ? 1 : 0;

  k_init<<<265, 256, 0, stream>>>(hidden, ws);
  if (use_xt) k_transpose_x<<<2048, 256, 0, stream>>>(input, ws + XT_OFF);

  ScanArgs sa{ws, input, out,
              Wzx0, Wzh0, bz0, Wrx0, Wrh0, br0, Wgx0, Wgh0, bg0,
              Wzx1, Wzh1, bz1, Wrx1, Wrh1, br1, Wgx1, Wgh1, bg1,
              Wout, bout, use_xt};
  k_scan<<<dim3(NWG), dim3(BDIM), 0, stream>>>(sa);

  k_hidden<<<256, 256, 0, stream>>>(ws, out);
}